// Round 2
// baseline (264.597 us; speedup 1.0000x reference)
//
#include <hip/hip_runtime.h>
#include <hip/hip_bf16.h>

// 9x9 VALID conv, 4096x4096 f32 -> 4088x4088 f32, + scalar bias.
// 64x64 output tile / 256-thread block; 72x72 input tile in LDS.
// Each thread: 4x4 outputs. Kernel taps via uniform s_load (SGPR operands).

#define H 4096
#define W 4096
#define OH 4088
#define OW 4088
#define TILE 64          // output tile edge
#define HALO 8           // KH-1
#define IN_T (TILE + HALO)   // 72
#define LDSW 76          // padded LDS row stride (multiple of 4 for float4)

__global__ __launch_bounds__(256, 2)
void conv9x9_kernel(const float* __restrict__ X,
                    const float* __restrict__ K,
                    const float* __restrict__ B,
                    float* __restrict__ out) {
    __shared__ float lds[IN_T * LDSW];

    const int tid = threadIdx.x;
    const int bx = blockIdx.x;     // tile col
    const int by = blockIdx.y;     // tile row
    const int in_row0 = by * TILE;
    const int in_col0 = bx * TILE;

    // ---- stage input tile (72x72) into LDS ----
    if (bx < (W / TILE - 1) && by < (H / TILE - 1)) {
        // interior: fully in-bounds, vectorized float4 loads (72 cols = 18 f4)
        for (int idx = tid; idx < IN_T * (IN_T / 4); idx += 256) {
            int r  = idx / (IN_T / 4);
            int c4 = idx - r * (IN_T / 4);
            float4 v = *(const float4*)(X + (size_t)(in_row0 + r) * W + in_col0 + c4 * 4);
            *(float4*)(&lds[r * LDSW + c4 * 4]) = v;
        }
    } else {
        // edge: scalar loads, clamped (clamped entries only feed OOB outputs)
        for (int idx = tid; idx < IN_T * IN_T; idx += 256) {
            int r = idx / IN_T;
            int c = idx - r * IN_T;
            int gr = in_row0 + r; if (gr > H - 1) gr = H - 1;
            int gc = in_col0 + c; if (gc > W - 1) gc = W - 1;
            lds[r * LDSW + c] = X[(size_t)gr * W + gc];
        }
    }
    __syncthreads();

    // ---- compute 4x4 per thread ----
    const int tx = tid & 15;       // 16 thread cols
    const int ty = tid >> 4;       // 16 thread rows
    const int lc = tx * 4;         // local col base
    const int lr = ty * 4;         // local row base

    const float bias = B[0];
    float acc[4][4];
#pragma unroll
    for (int i = 0; i < 4; ++i)
#pragma unroll
        for (int j = 0; j < 4; ++j)
            acc[i][j] = bias;

#pragma unroll
    for (int rr = 0; rr < 12; ++rr) {   // 12 distinct input rows per thread
        const float* rp = &lds[(lr + rr) * LDSW + lc];
        float seg[12];
#pragma unroll
        for (int q = 0; q < 3; ++q) {
            float4 v = *(const float4*)(rp + q * 4);
            seg[q * 4 + 0] = v.x;
            seg[q * 4 + 1] = v.y;
            seg[q * 4 + 2] = v.z;
            seg[q * 4 + 3] = v.w;
        }
#pragma unroll
        for (int kr = 0; kr < 9; ++kr) {
            // valid when output row i = rr - kr in [0,3]; compile-time after unroll
            if (kr > rr || kr < rr - 3) continue;
            const int i = rr - kr;
#pragma unroll
            for (int kc = 0; kc < 9; ++kc) {
                const float kv = K[kr * 9 + kc];   // uniform -> s_load / SGPR
#pragma unroll
                for (int j = 0; j < 4; ++j)
                    acc[i][j] = fmaf(kv, seg[kc + j], acc[i][j]);
            }
        }
    }

    // ---- store (float4, bounds-checked; OW % 4 == 0 so f4 is all-or-nothing) ----
    const int orow0 = by * TILE + lr;
    const int ocol  = bx * TILE + lc;
    if (ocol < OW) {
#pragma unroll
        for (int i = 0; i < 4; ++i) {
            const int orow = orow0 + i;
            if (orow < OH) {
                float4 v = { acc[i][0], acc[i][1], acc[i][2], acc[i][3] };
                *(float4*)(out + (size_t)orow * OW + ocol) = v;
            }
        }
    }
}

extern "C" void kernel_launch(void* const* d_in, const int* in_sizes, int n_in,
                              void* d_out, int out_size, void* d_ws, size_t ws_size,
                              hipStream_t stream) {
    const float* X = (const float*)d_in[0];
    const float* K = (const float*)d_in[1];
    const float* B = (const float*)d_in[2];
    float* out = (float*)d_out;

    dim3 grid(W / TILE, H / TILE);   // 64 x 64 (covers 4096; edges bounds-checked)
    dim3 block(256);
    conv9x9_kernel<<<grid, block, 0, stream>>>(X, K, B, out);
}

// Round 3
// 150.337 us; speedup vs baseline: 1.7600x; 1.7600x over previous
//
#include <hip/hip_runtime.h>
#include <hip/hip_bf16.h>

// 9x9 VALID conv, 4096x4096 f32 -> 4088x4088 f32, + scalar bias.
// No-LDS design: each wave = 4 output rows x 256 cols; each thread a 4x4
// micro-tile via 36 independent global float4 loads (L1/L2 provide reuse).
// No barriers; taps uniform -> SGPR; 1KB-contiguous stores per wave-row.

#define H 4096
#define W 4096
#define OH 4088
#define OW 4088

__global__ __launch_bounds__(256, 4)
void conv9x9_kernel(const float* __restrict__ X,
                    const float* __restrict__ K,
                    const float* __restrict__ B,
                    float* __restrict__ out) {
    const int tid = threadIdx.x;
    const int tx = tid & 63;        // 64 lanes across columns
    const int ty = tid >> 6;        // 4 waves down rows
    const int bx = blockIdx.x;      // 16 col-tiles of 256
    const int by = blockIdx.y;      // 256 row-tiles of 16

    const int r0 = by * 16 + ty * 4;    // first output row of this thread
    const int c0 = bx * 256 + tx * 4;   // first output col of this thread

    const float bias = B[0];
    float acc[4][4];
#pragma unroll
    for (int i = 0; i < 4; ++i)
#pragma unroll
        for (int j = 0; j < 4; ++j)
            acc[i][j] = bias;

    // interior blocks never touch OOB input (by=254: max row 4076+11=4087;
    // bx=14: max col 3836+11=3847). Edge blocks clamp; clamped values only
    // ever feed outputs that are masked at store time.
    const bool interior = (bx < (W / 256 - 1)) && (by < (H / 16 - 1));

    if (interior) {
#pragma unroll
        for (int rr = 0; rr < 12; ++rr) {
            const float* rp = X + (size_t)(r0 + rr) * W + c0;
            float seg[12];
#pragma unroll
            for (int q = 0; q < 3; ++q) {
                float4 v = *(const float4*)(rp + q * 4);
                seg[q * 4 + 0] = v.x; seg[q * 4 + 1] = v.y;
                seg[q * 4 + 2] = v.z; seg[q * 4 + 3] = v.w;
            }
#pragma unroll
            for (int kr = 0; kr < 9; ++kr) {
                if (kr > rr || kr < rr - 3) continue;   // compile-time pruned
                const int i = rr - kr;
#pragma unroll
                for (int kc = 0; kc < 9; ++kc) {
                    const float kv = K[kr * 9 + kc];    // uniform -> SGPR
#pragma unroll
                    for (int j = 0; j < 4; ++j)
                        acc[i][j] = fmaf(kv, seg[kc + j], acc[i][j]);
                }
            }
        }
    } else {
#pragma unroll
        for (int rr = 0; rr < 12; ++rr) {
            int gr = r0 + rr; if (gr > H - 1) gr = H - 1;
            const float* rowp = X + (size_t)gr * W;
            float seg[12];
#pragma unroll
            for (int q = 0; q < 3; ++q) {
                int gc = c0 + q * 4; if (gc > W - 4) gc = W - 4;  // keep f4 in-bounds
                float4 v = *(const float4*)(rowp + gc);
                seg[q * 4 + 0] = v.x; seg[q * 4 + 1] = v.y;
                seg[q * 4 + 2] = v.z; seg[q * 4 + 3] = v.w;
            }
#pragma unroll
            for (int kr = 0; kr < 9; ++kr) {
                if (kr > rr || kr < rr - 3) continue;
                const int i = rr - kr;
#pragma unroll
                for (int kc = 0; kc < 9; ++kc) {
                    const float kv = K[kr * 9 + kc];
#pragma unroll
                    for (int j = 0; j < 4; ++j)
                        acc[i][j] = fmaf(kv, seg[kc + j], acc[i][j]);
                }
            }
        }
    }

    // store: per wave-row 64 lanes x float4 = 1KB contiguous.
    // c0 % 4 == 0 and OW % 4 == 0 -> a float4 is fully in or fully out.
    if (c0 < OW) {
#pragma unroll
        for (int i = 0; i < 4; ++i) {
            const int orow = r0 + i;
            if (orow < OH) {
                float4 v = { acc[i][0], acc[i][1], acc[i][2], acc[i][3] };
                *(float4*)(out + (size_t)orow * OW + c0) = v;
            }
        }
    }
}

extern "C" void kernel_launch(void* const* d_in, const int* in_sizes, int n_in,
                              void* d_out, int out_size, void* d_ws, size_t ws_size,
                              hipStream_t stream) {
    const float* X = (const float*)d_in[0];
    const float* K = (const float*)d_in[1];
    const float* B = (const float*)d_in[2];
    float* out = (float*)d_out;

    dim3 grid(W / 256, H / 16);   // 16 x 256 = 4096 blocks
    dim3 block(256);
    conv9x9_kernel<<<grid, block, 0, stream>>>(X, K, B, out);
}